// Round 2
// baseline (577.846 us; speedup 1.0000x reference)
//
#include <hip/hip_runtime.h>
#include <hip/hip_bf16.h>

#define N_NODES 50000
#define E_EDGES 800000
#define ET (E_EDGES + N_NODES)   /* 850000 edges incl self loops */
#define IN_DIM 128
#define HID 96
#define HEADS 2
#define CPH 48
#define NEG_SLOPE 0.2f
#define LN_EPS 1e-5f
#define ROWS_P 16
#define ROWS_X 16

typedef __hip_bfloat16 bf16;
typedef short short8 __attribute__((ext_vector_type(8)));

__device__ __forceinline__ float us2f(unsigned short u) {
    union { unsigned int i; float f; } v; v.i = ((unsigned int)u) << 16; return v.f;
}

// ---------------- CSR build ----------------
__global__ void k_hist(const int* __restrict__ ei, int* __restrict__ deg) {
    int e = blockIdx.x * blockDim.x + threadIdx.x;
    if (e >= ET) return;
    int dst = (e < E_EDGES) ? ei[E_EDGES + e] : (e - E_EDGES);
    atomicAdd(&deg[dst], 1);
}

__global__ __launch_bounds__(1024) void k_scan(const int* __restrict__ deg,
                                               int* __restrict__ rowstart,
                                               int* __restrict__ cursor) {
    __shared__ int wsum[16];
    __shared__ int s_carry;
    int t = threadIdx.x, lane = t & 63, w = t >> 6;
    if (t == 0) s_carry = 0;
    __syncthreads();
    for (int base = 0; base < N_NODES; base += 1024) {
        int i = base + t;
        int v = (i < N_NODES) ? deg[i] : 0;
        int sv = v;
        for (int o = 1; o < 64; o <<= 1) { int u = __shfl_up(sv, o, 64); if (lane >= o) sv += u; }
        if (lane == 63) wsum[w] = sv;
        __syncthreads();
        if (w == 0) {
            int val = (lane < 16) ? wsum[lane] : 0;
            int s2 = val;
            for (int o = 1; o < 64; o <<= 1) { int u = __shfl_up(s2, o, 64); if (lane >= o) s2 += u; }
            if (lane < 16) wsum[lane] = s2 - val;            // exclusive wave prefix
        }
        __syncthreads();
        int excl = s_carry + wsum[w] + (sv - v);
        if (i < N_NODES) { rowstart[i] = excl; cursor[i] = excl; }
        __syncthreads();
        if (t == 1023) s_carry += wsum[15] + sv;
        __syncthreads();
    }
    if (t == 0) rowstart[N_NODES] = ET;
}

__global__ void k_scatter(const int* __restrict__ ei, int* __restrict__ cursor,
                          int* __restrict__ csr_src, int* __restrict__ csr_dst) {
    int e = blockIdx.x * blockDim.x + threadIdx.x;
    if (e >= ET) return;
    int src, dst;
    if (e < E_EDGES) { src = ei[e]; dst = ei[E_EDGES + e]; }
    else             { src = dst = e - E_EDGES; }
    int pos = atomicAdd(&cursor[dst], 1);
    csr_src[pos] = src;
    csr_dst[pos] = dst;
}

// ---------------- input proj + LN + ReLU (16 nodes/block) ----------------
__global__ __launch_bounds__(128) void k_in_proj(const float* __restrict__ x,
                                                 const float* __restrict__ Wp,
                                                 const float* __restrict__ bp,
                                                 const float* __restrict__ g0,
                                                 const float* __restrict__ b0,
                                                 float* __restrict__ h) {
    int t = threadIdx.x;
    int n0 = blockIdx.x * ROWS_P;
    __shared__ float sx[ROWS_P][IN_DIM];   // 8 KB
    __shared__ float sh[ROWS_P][HID];      // 6 KB
    const float4* xin = (const float4*)(x + (long)n0 * IN_DIM);
    float4* sx4 = (float4*)&sx[0][0];
    #pragma unroll
    for (int i = 0; i < (ROWS_P * IN_DIM / 4) / 128; i++)   // 4 iters
        sx4[i * 128 + t] = xin[i * 128 + t];
    __syncthreads();
    if (t < HID) {
        float acc[ROWS_P];
        float bias = bp[t];
        #pragma unroll
        for (int r = 0; r < ROWS_P; r++) acc[r] = bias;
        for (int k = 0; k < IN_DIM; k++) {
            float wv = Wp[k * HID + t];
            #pragma unroll
            for (int r = 0; r < ROWS_P; r++) acc[r] += sx[r][k] * wv;
        }
        #pragma unroll
        for (int r = 0; r < ROWS_P; r++) sh[r][t] = acc[r];
    }
    __syncthreads();
    int lane = t & 63, w = t >> 6;
    float ga = g0[lane], ba = b0[lane];
    float gb = (lane < 32) ? g0[64 + lane] : 0.f;
    float bb = (lane < 32) ? b0[64 + lane] : 0.f;
    #pragma unroll
    for (int r8 = 0; r8 < ROWS_P / 2; r8++) {
        int r = w * (ROWS_P / 2) + r8;
        float v0 = sh[r][lane];
        float v1 = (lane < 32) ? sh[r][64 + lane] : 0.f;
        float s = v0 + v1, sq = v0 * v0 + v1 * v1;
        for (int o = 32; o > 0; o >>= 1) { s += __shfl_xor(s, o, 64); sq += __shfl_xor(sq, o, 64); }
        float mu = s / (float)HID;
        float var = sq / (float)HID - mu * mu;
        float rstd = rsqrtf(var + LN_EPS);
        float y0 = (v0 - mu) * rstd * ga + ba;
        h[(long)(n0 + r) * HID + lane] = fmaxf(y0, 0.f);
        if (lane < 32) {
            float y1 = (v1 - mu) * rstd * gb + bb;
            h[(long)(n0 + r) * HID + 64 + lane] = fmaxf(y1, 0.f);
        }
    }
}

// ---------------- per-layer node transform (xl = h@Wl, xr = h@Wr), 16 nodes/block ----------------
__global__ __launch_bounds__(256) void k_xfm(const float* __restrict__ h,
                                             const float* __restrict__ Wl,
                                             const float* __restrict__ Wr,
                                             bf16* __restrict__ xl,
                                             bf16* __restrict__ xr) {
    int t = threadIdx.x;
    int n0 = blockIdx.x * ROWS_X;
    __shared__ float sh[ROWS_X][HID];      // 6 KB
    const float* hin = h + (long)n0 * HID;
    for (int i = t; i < ROWS_X * HID; i += 256) ((float*)sh)[i] = hin[i];
    __syncthreads();
    if (t < 2 * HID) {
        const float* W = (t < HID) ? Wl : Wr;
        int c = (t < HID) ? t : t - HID;
        float acc[ROWS_X];
        #pragma unroll
        for (int r = 0; r < ROWS_X; r++) acc[r] = 0.f;
        for (int k = 0; k < HID; k++) {
            float wv = W[k * HID + c];
            #pragma unroll
            for (int r = 0; r < ROWS_X; r++) acc[r] += sh[r][k] * wv;
        }
        bf16* dst = (t < HID) ? xl : xr;
        #pragma unroll
        for (int r = 0; r < ROWS_X; r++) dst[(long)(n0 + r) * HID + c] = __float2bfloat16(acc[r]);
    }
}

// ---------------- edge scores (CSR order) ----------------
__global__ __launch_bounds__(256) void k_edge_score(const int* __restrict__ csr_src,
                                                    const int* __restrict__ csr_dst,
                                                    const bf16* __restrict__ xl,
                                                    const bf16* __restrict__ xr,
                                                    const float* __restrict__ att,
                                                    float* __restrict__ score) {
    __shared__ float s_att[HEADS * CPH];
    int t = threadIdx.x;
    if (t < HEADS * CPH) s_att[t] = att[t];
    __syncthreads();
    long tid = (long)blockIdx.x * blockDim.x + t;
    if (tid >= (long)ET * HEADS) return;
    int pos = (int)(tid >> 1);
    int hh  = (int)(tid & 1);
    int src = csr_src[pos], dst = csr_dst[pos];
    const short8* pl = (const short8*)(xl + (long)src * HID + hh * CPH);
    const short8* pr = (const short8*)(xr + (long)dst * HID + hh * CPH);
    const float* pa = s_att + hh * CPH;
    float s = 0.f;
    #pragma unroll
    for (int v = 0; v < 6; v++) {
        short8 a = pl[v], b = pr[v];
        #pragma unroll
        for (int j = 0; j < 8; j++) {
            float xv = us2f((unsigned short)a[j]) + us2f((unsigned short)b[j]);
            xv = (xv > 0.f) ? xv : NEG_SLOPE * xv;
            s += pa[v * 8 + j] * xv;
        }
    }
    score[(long)pos * HEADS + hh] = s;
}

// ---------------- node: online softmax + aggregate + LN + ELU + residual ----------------
__global__ __launch_bounds__(128) void k_node_agg(const int* __restrict__ rowstart,
                                                  const int* __restrict__ csr_src,
                                                  const float* __restrict__ score,
                                                  const bf16* __restrict__ xl,
                                                  const float* __restrict__ gs,
                                                  const float* __restrict__ bs,
                                                  float* __restrict__ h,
                                                  float* __restrict__ out,
                                                  int write_out) {
    int n = blockIdx.x, t = threadIdx.x;
    int lane = t & 63, w = t >> 6;
    int rs = rowstart[n], re = rowstart[n + 1];
    __shared__ float s_p[64 * HEADS];   // s_p[i*2+h]
    __shared__ int   s_src[64];
    __shared__ float s_scale[HEADS];
    __shared__ float s_D[HEADS];
    __shared__ float red[128];
    float M = -INFINITY, D = 0.f;       // wave w tracks head w
    float acc = 0.f;
    int c = t;
    int ch = (c < CPH) ? 0 : 1;

    for (int base = rs; base < re; base += 64) {
        int L = min(64, re - base);
        if (t < L) s_src[t] = csr_src[base + t];
        if (t < 2 * L) s_p[t] = score[(long)base * HEADS + t];
        __syncthreads();
        {
            float v = (lane < L) ? s_p[lane * 2 + w] : -INFINITY;
            float m = v;
            for (int o = 32; o > 0; o >>= 1) m = fmaxf(m, __shfl_xor(m, o, 64));
            float newM = fmaxf(M, m);
            float scale = expf(M - newM);            // exp(-inf)=0 on first chunk
            float p = (lane < L) ? expf(v - newM) : 0.f;
            if (lane < L) s_p[lane * 2 + w] = p;
            float sum = p;
            for (int o = 32; o > 0; o >>= 1) sum += __shfl_xor(sum, o, 64);
            D = D * scale + sum;
            M = newM;
            if (lane == 0) s_scale[w] = scale;
        }
        __syncthreads();
        if (c < HID) {
            acc *= s_scale[ch];
            #pragma unroll 4
            for (int i = 0; i < L; i++) {
                float p = s_p[i * 2 + ch];
                acc += p * __bfloat162float(xl[(long)s_src[i] * HID + c]);
            }
        }
        __syncthreads();
    }
    if (lane == 0) s_D[w] = D;
    __syncthreads();
    float outv = (c < HID) ? (acc / s_D[ch]) : 0.f;
    red[t] = outv; __syncthreads();
    for (int s = 64; s > 0; s >>= 1) { if (t < s) red[t] += red[t + s]; __syncthreads(); }
    float mu = red[0] / HID; __syncthreads();
    float d0 = (c < HID) ? (outv - mu) : 0.f;
    red[t] = d0 * d0; __syncthreads();
    for (int s = 64; s > 0; s >>= 1) { if (t < s) red[t] += red[t + s]; __syncthreads(); }
    float var = red[0] / HID;
    if (c < HID) {
        float y = (outv - mu) * rsqrtf(var + LN_EPS) * gs[c] + bs[c];
        float hn = (y > 0.f) ? y : expm1f(y);
        float hv = h[(long)n * HID + c] + hn;
        h[(long)n * HID + c] = hv;
        if (write_out) out[(long)n * HID + c] = hv;
    }
}

extern "C" void kernel_launch(void* const* d_in, const int* in_sizes, int n_in,
                              void* d_out, int out_size, void* d_ws, size_t ws_size,
                              hipStream_t stream) {
    const float* x   = (const float*)d_in[0];
    const int*   ei  = (const int*)d_in[1];
    const float* Wp  = (const float*)d_in[2];
    const float* bp  = (const float*)d_in[3];
    const float* g0  = (const float*)d_in[4];
    const float* b0  = (const float*)d_in[5];
    const float* Wl  = (const float*)d_in[6];
    const float* Wr  = (const float*)d_in[7];
    const float* att = (const float*)d_in[8];
    const float* gs  = (const float*)d_in[9];
    const float* bs  = (const float*)d_in[10];
    float* out = (float*)d_out;

    char* wsp = (char*)d_ws;
    size_t off = 0;
    auto alloc = [&](size_t bytes) { void* p = wsp + off; off += (bytes + 255) / 256 * 256; return p; };
    float* h      = (float*)alloc((size_t)N_NODES * HID * 4);
    bf16*  xl     = (bf16*) alloc((size_t)N_NODES * HID * 2);
    bf16*  xr     = (bf16*) alloc((size_t)N_NODES * HID * 2);
    float* score  = (float*)alloc((size_t)ET * HEADS * 4);
    int*   deg    = (int*)  alloc((size_t)N_NODES * 4);
    int*   rowst  = (int*)  alloc((size_t)(N_NODES + 1) * 4);
    int*   cursor = (int*)  alloc((size_t)N_NODES * 4);
    int*   csr_src= (int*)  alloc((size_t)ET * 4);
    int*   csr_dst= (int*)  alloc((size_t)ET * 4);

    hipMemsetAsync(deg, 0, (size_t)N_NODES * 4, stream);
    k_hist<<<(ET + 255) / 256, 256, 0, stream>>>(ei, deg);
    k_scan<<<1, 1024, 0, stream>>>(deg, rowst, cursor);
    k_scatter<<<(ET + 255) / 256, 256, 0, stream>>>(ei, cursor, csr_src, csr_dst);
    k_in_proj<<<N_NODES / ROWS_P, 128, 0, stream>>>(x, Wp, bp, g0, b0, h);
    for (int L = 0; L < 2; L++) {
        k_xfm<<<N_NODES / ROWS_X, 256, 0, stream>>>(h, Wl + (size_t)L * HID * HID,
                                                    Wr + (size_t)L * HID * HID, xl, xr);
        long nsc = (long)ET * HEADS;
        k_edge_score<<<(int)((nsc + 255) / 256), 256, 0, stream>>>(csr_src, csr_dst, xl, xr,
                                                                   att + (size_t)L * HEADS * CPH, score);
        k_node_agg<<<N_NODES, 128, 0, stream>>>(rowst, csr_src, score, xl,
                                                gs + (size_t)L * HID, bs + (size_t)L * HID,
                                                h, out, (L == 1) ? 1 : 0);
    }
}

// Round 3
// 421.795 us; speedup vs baseline: 1.3700x; 1.3700x over previous
//
#include <hip/hip_runtime.h>
#include <hip/hip_bf16.h>

#define N_NODES 50000
#define E_EDGES 800000
#define ET (E_EDGES + N_NODES)   /* 850000 edges incl self loops */
#define IN_DIM 128
#define HID 96
#define HEADS 2
#define CPH 48
#define NEG_SLOPE 0.2f
#define LN_EPS 1e-5f

typedef __hip_bfloat16 bf16;
typedef short short8 __attribute__((ext_vector_type(8)));
typedef short bf16x8 __attribute__((ext_vector_type(8)));
typedef float f32x4 __attribute__((ext_vector_type(4)));

__device__ __forceinline__ float us2f(unsigned short u) {
    union { unsigned int i; float f; } v; v.i = ((unsigned int)u) << 16; return v.f;
}
__device__ __forceinline__ unsigned short f2bf(float f) {
    union { float f; unsigned int i; } u; u.f = f;
    unsigned int r = u.i + 0x7FFFu + ((u.i >> 16) & 1u);
    return (unsigned short)(r >> 16);
}

// ---------------- CSR build ----------------
__global__ void k_hist(const int* __restrict__ ei, int* __restrict__ deg) {
    int e = blockIdx.x * blockDim.x + threadIdx.x;
    if (e >= ET) return;
    int dst = (e < E_EDGES) ? ei[E_EDGES + e] : (e - E_EDGES);
    atomicAdd(&deg[dst], 1);
}

__global__ __launch_bounds__(1024) void k_scan(const int* __restrict__ deg,
                                               int* __restrict__ rowstart,
                                               int* __restrict__ cursor) {
    __shared__ int wsum[16];
    __shared__ int s_carry;
    int t = threadIdx.x, lane = t & 63, w = t >> 6;
    if (t == 0) s_carry = 0;
    __syncthreads();
    for (int base = 0; base < N_NODES; base += 1024) {
        int i = base + t;
        int v = (i < N_NODES) ? deg[i] : 0;
        int sv = v;
        for (int o = 1; o < 64; o <<= 1) { int u = __shfl_up(sv, o, 64); if (lane >= o) sv += u; }
        if (lane == 63) wsum[w] = sv;
        __syncthreads();
        if (w == 0) {
            int val = (lane < 16) ? wsum[lane] : 0;
            int s2 = val;
            for (int o = 1; o < 64; o <<= 1) { int u = __shfl_up(s2, o, 64); if (lane >= o) s2 += u; }
            if (lane < 16) wsum[lane] = s2 - val;            // exclusive wave prefix
        }
        __syncthreads();
        int excl = s_carry + wsum[w] + (sv - v);
        if (i < N_NODES) { rowstart[i] = excl; cursor[i] = excl; }
        __syncthreads();
        if (t == 1023) s_carry += wsum[15] + sv;
        __syncthreads();
    }
    if (t == 0) rowstart[N_NODES] = ET;
}

__global__ void k_scatter(const int* __restrict__ ei, int* __restrict__ cursor,
                          int* __restrict__ csr_src, int* __restrict__ csr_dst) {
    int e = blockIdx.x * blockDim.x + threadIdx.x;
    if (e >= ET) return;
    int src, dst;
    if (e < E_EDGES) { src = ei[e]; dst = ei[E_EDGES + e]; }
    else             { src = dst = e - E_EDGES; }
    int pos = atomicAdd(&cursor[dst], 1);
    csr_src[pos] = src;
    csr_dst[pos] = dst;
}

// ---------------- weight prep: pack into 16x16x32 B-fragment order, bf16 ----------------
// frag idx -> j = idx&7, lane=(idx>>3)&63, nt=(idx>>9)%NT, ks=(idx>>9)/NT
// source: k = ks*32 + (lane>>4)*8 + j ; col = nt*16 + (lane&15)
__global__ void k_wprep(const float* __restrict__ W0, const float* __restrict__ W1,
                        unsigned short* __restrict__ out, int NT, int total) {
    int idx = blockIdx.x * blockDim.x + threadIdx.x;
    if (idx >= total) return;
    int j = idx & 7, lane = (idx >> 3) & 63;
    int nt = (idx >> 9) % NT, ks = (idx >> 9) / NT;
    int k = ks * 32 + ((lane >> 4) << 3) + j;
    int col = nt * 16 + (lane & 15);
    float v = (col < HID) ? W0[k * HID + col] : W1[k * HID + col - HID];
    out[idx] = f2bf(v);
}

// ---------------- MFMA GEMM: A[f32, MxK] @ Bfrag -> proj(LN+ReLU->h) or xfm(->xl,xr bf16) ----------------
template<int K, int NT, bool PROJ>
__global__ __launch_bounds__(256) void k_gemm(const float* __restrict__ A,
                                              const unsigned short* __restrict__ Bfrag,
                                              const float* __restrict__ bp,
                                              const float* __restrict__ g0,
                                              const float* __restrict__ b0,
                                              float* __restrict__ hout,
                                              bf16* __restrict__ xl,
                                              bf16* __restrict__ xr) {
    constexpr int KS = K / 32;
    int t = threadIdx.x, l = t & 63, w = t >> 6;
    int row0 = blockIdx.x * 64 + w * 16;
    int arow = row0 + (l & 15);
    if (arow > N_NODES - 1) arow = N_NODES - 1;
    int kb = (l >> 4) * 8;
    const float* ap = A + (long)arow * K + kb;
    bf16x8 a[KS];
    #pragma unroll
    for (int ks = 0; ks < KS; ks++) {
        float4 f0 = *(const float4*)(ap + ks * 32);
        float4 f1 = *(const float4*)(ap + ks * 32 + 4);
        bf16x8 av;
        av[0] = (short)f2bf(f0.x); av[1] = (short)f2bf(f0.y);
        av[2] = (short)f2bf(f0.z); av[3] = (short)f2bf(f0.w);
        av[4] = (short)f2bf(f1.x); av[5] = (short)f2bf(f1.y);
        av[6] = (short)f2bf(f1.z); av[7] = (short)f2bf(f1.w);
        a[ks] = av;
    }
    f32x4 acc[NT];
    #pragma unroll
    for (int nt = 0; nt < NT; nt++) acc[nt] = (f32x4){0.f, 0.f, 0.f, 0.f};
    #pragma unroll
    for (int nt = 0; nt < NT; nt++) {
        #pragma unroll
        for (int ks = 0; ks < KS; ks++) {
            bf16x8 b = *(const bf16x8*)(Bfrag + (((long)(ks * NT + nt) * 64 + l) << 3));
            acc[nt] = __builtin_amdgcn_mfma_f32_16x16x32_bf16(a[ks], b, acc[nt], 0, 0, 0);
        }
    }
    int rg = l >> 4, cl = l & 15;
    if constexpr (PROJ) {
        float bpv[NT], g0v[NT], b0v[NT];
        #pragma unroll
        for (int nt = 0; nt < NT; nt++) {
            int col = nt * 16 + cl;
            bpv[nt] = bp[col]; g0v[nt] = g0[col]; b0v[nt] = b0[col];
        }
        #pragma unroll
        for (int r = 0; r < 4; r++) {
            float s = 0.f, sq = 0.f;
            #pragma unroll
            for (int nt = 0; nt < NT; nt++) {
                float v = acc[nt][r] + bpv[nt];
                acc[nt][r] = v; s += v; sq += v * v;
            }
            #pragma unroll
            for (int o = 1; o <= 8; o <<= 1) { s += __shfl_xor(s, o, 64); sq += __shfl_xor(sq, o, 64); }
            float mu = s / (float)HID;
            float var = sq / (float)HID - mu * mu;
            float rstd = rsqrtf(var + LN_EPS);
            int row = row0 + rg * 4 + r;
            if (row < N_NODES) {
                #pragma unroll
                for (int nt = 0; nt < NT; nt++) {
                    float y = (acc[nt][r] - mu) * rstd * g0v[nt] + b0v[nt];
                    hout[(long)row * HID + nt * 16 + cl] = fmaxf(y, 0.f);
                }
            }
        }
    } else {
        #pragma unroll
        for (int r = 0; r < 4; r++) {
            int row = row0 + rg * 4 + r;
            if (row < N_NODES) {
                #pragma unroll
                for (int nt = 0; nt < NT; nt++) {
                    int col = nt * 16 + cl;
                    unsigned short v = f2bf(acc[nt][r]);
                    if (col < HID) ((unsigned short*)xl)[(long)row * HID + col] = v;
                    else           ((unsigned short*)xr)[(long)row * HID + col - HID] = v;
                }
            }
        }
    }
}

// ---------------- edge scores (CSR order) ----------------
__global__ __launch_bounds__(256) void k_edge_score(const int* __restrict__ csr_src,
                                                    const int* __restrict__ csr_dst,
                                                    const bf16* __restrict__ xl,
                                                    const bf16* __restrict__ xr,
                                                    const float* __restrict__ att,
                                                    float* __restrict__ score) {
    __shared__ float s_att[HEADS * CPH];
    int t = threadIdx.x;
    if (t < HEADS * CPH) s_att[t] = att[t];
    __syncthreads();
    long tid = (long)blockIdx.x * blockDim.x + t;
    if (tid >= (long)ET * HEADS) return;
    int pos = (int)(tid >> 1);
    int hh  = (int)(tid & 1);
    int src = csr_src[pos], dst = csr_dst[pos];
    const short8* pl = (const short8*)(xl + (long)src * HID + hh * CPH);
    const short8* pr = (const short8*)(xr + (long)dst * HID + hh * CPH);
    const float* pa = s_att + hh * CPH;
    float s = 0.f;
    #pragma unroll
    for (int v = 0; v < 6; v++) {
        short8 a = pl[v], b = pr[v];
        #pragma unroll
        for (int j = 0; j < 8; j++) {
            float xv = us2f((unsigned short)a[j]) + us2f((unsigned short)b[j]);
            xv = (xv > 0.f) ? xv : NEG_SLOPE * xv;
            s += pa[v * 8 + j] * xv;
        }
    }
    score[(long)pos * HEADS + hh] = s;
}

// ---------------- node: online softmax + aggregate + LN + ELU + residual ----------------
__global__ __launch_bounds__(128) void k_node_agg(const int* __restrict__ rowstart,
                                                  const int* __restrict__ csr_src,
                                                  const float* __restrict__ score,
                                                  const bf16* __restrict__ xl,
                                                  const float* __restrict__ gs,
                                                  const float* __restrict__ bs,
                                                  float* __restrict__ h,
                                                  float* __restrict__ out,
                                                  int write_out) {
    int n = blockIdx.x, t = threadIdx.x;
    int lane = t & 63, w = t >> 6;
    int rs = rowstart[n], re = rowstart[n + 1];
    __shared__ float s_p[64 * HEADS];   // s_p[i*2+h]
    __shared__ int   s_src[64];
    __shared__ float s_scale[HEADS];
    __shared__ float s_D[HEADS];
    __shared__ float red[128];
    float M = -INFINITY, D = 0.f;       // wave w tracks head w
    float acc = 0.f;
    int c = t;
    int ch = (c < CPH) ? 0 : 1;

    for (int base = rs; base < re; base += 64) {
        int L = min(64, re - base);
        if (t < L) s_src[t] = csr_src[base + t];
        if (t < 2 * L) s_p[t] = score[(long)base * HEADS + t];
        __syncthreads();
        {
            float v = (lane < L) ? s_p[lane * 2 + w] : -INFINITY;
            float m = v;
            for (int o = 32; o > 0; o >>= 1) m = fmaxf(m, __shfl_xor(m, o, 64));
            float newM = fmaxf(M, m);
            float scale = expf(M - newM);            // exp(-inf)=0 on first chunk
            float p = (lane < L) ? expf(v - newM) : 0.f;
            if (lane < L) s_p[lane * 2 + w] = p;
            float sum = p;
            for (int o = 32; o > 0; o >>= 1) sum += __shfl_xor(sum, o, 64);
            D = D * scale + sum;
            M = newM;
            if (lane == 0) s_scale[w] = scale;
        }
        __syncthreads();
        if (c < HID) {
            acc *= s_scale[ch];
            #pragma unroll 4
            for (int i = 0; i < L; i++) {
                float p = s_p[i * 2 + ch];
                acc += p * __bfloat162float(xl[(long)s_src[i] * HID + c]);
            }
        }
        __syncthreads();
    }
    if (lane == 0) s_D[w] = D;
    __syncthreads();
    float outv = (c < HID) ? (acc / s_D[ch]) : 0.f;
    red[t] = outv; __syncthreads();
    for (int s = 64; s > 0; s >>= 1) { if (t < s) red[t] += red[t + s]; __syncthreads(); }
    float mu = red[0] / HID; __syncthreads();
    float d0 = (c < HID) ? (outv - mu) : 0.f;
    red[t] = d0 * d0; __syncthreads();
    for (int s = 64; s > 0; s >>= 1) { if (t < s) red[t] += red[t + s]; __syncthreads(); }
    float var = red[0] / HID;
    if (c < HID) {
        float y = (outv - mu) * rsqrtf(var + LN_EPS) * gs[c] + bs[c];
        float hn = (y > 0.f) ? y : expm1f(y);
        float hv = h[(long)n * HID + c] + hn;
        h[(long)n * HID + c] = hv;
        if (write_out) out[(long)n * HID + c] = hv;
    }
}

extern "C" void kernel_launch(void* const* d_in, const int* in_sizes, int n_in,
                              void* d_out, int out_size, void* d_ws, size_t ws_size,
                              hipStream_t stream) {
    const float* x   = (const float*)d_in[0];
    const int*   ei  = (const int*)d_in[1];
    const float* Wp  = (const float*)d_in[2];
    const float* bp  = (const float*)d_in[3];
    const float* g0  = (const float*)d_in[4];
    const float* b0  = (const float*)d_in[5];
    const float* Wl  = (const float*)d_in[6];
    const float* Wr  = (const float*)d_in[7];
    const float* att = (const float*)d_in[8];
    const float* gs  = (const float*)d_in[9];
    const float* bs  = (const float*)d_in[10];
    float* out = (float*)d_out;

    char* wsp = (char*)d_ws;
    size_t off = 0;
    auto alloc = [&](size_t bytes) { void* p = wsp + off; off += (bytes + 255) / 256 * 256; return p; };
    float* h        = (float*)alloc((size_t)N_NODES * HID * 4);
    bf16*  xl       = (bf16*) alloc((size_t)N_NODES * HID * 2);
    bf16*  xr       = (bf16*) alloc((size_t)N_NODES * HID * 2);
    float* score    = (float*)alloc((size_t)ET * HEADS * 4);
    int*   deg      = (int*)  alloc((size_t)N_NODES * 4);
    int*   rowst    = (int*)  alloc((size_t)(N_NODES + 1) * 4);
    int*   cursor   = (int*)  alloc((size_t)N_NODES * 4);
    int*   csr_src  = (int*)  alloc((size_t)ET * 4);
    int*   csr_dst  = (int*)  alloc((size_t)ET * 4);
    unsigned short* wp_frag = (unsigned short*)alloc((size_t)IN_DIM * HID * 2);          // 4 ks * 6 nt * 512
    unsigned short* wc_frag = (unsigned short*)alloc((size_t)2 * HID * 2 * HID * 2);     // per layer: 3 ks * 12 nt * 512

    hipMemsetAsync(deg, 0, (size_t)N_NODES * 4, stream);
    k_hist<<<(ET + 255) / 256, 256, 0, stream>>>(ei, deg);
    k_scan<<<1, 1024, 0, stream>>>(deg, rowst, cursor);
    k_scatter<<<(ET + 255) / 256, 256, 0, stream>>>(ei, cursor, csr_src, csr_dst);

    // weight packing
    const int WPTOT = IN_DIM * HID;            // 12288 (KS=4, NT=6)
    const int WCTOT = HID * 2 * HID;           // 18432 per layer (KS=3, NT=12)
    k_wprep<<<(WPTOT + 255) / 256, 256, 0, stream>>>(Wp, Wp, wp_frag, 6, WPTOT);
    for (int L = 0; L < 2; L++)
        k_wprep<<<(WCTOT + 255) / 256, 256, 0, stream>>>(Wl + (size_t)L * HID * HID,
                                                         Wr + (size_t)L * HID * HID,
                                                         wc_frag + (size_t)L * WCTOT, 12, WCTOT);

    const int GBLK = (N_NODES + 63) / 64;
    k_gemm<IN_DIM, 6, true><<<GBLK, 256, 0, stream>>>(x, wp_frag, bp, g0, b0, h, nullptr, nullptr);
    for (int L = 0; L < 2; L++) {
        k_gemm<HID, 12, false><<<GBLK, 256, 0, stream>>>(h, wc_frag + (size_t)L * WCTOT,
                                                         nullptr, nullptr, nullptr, nullptr, xl, xr);
        long nsc = (long)ET * HEADS;
        k_edge_score<<<(int)((nsc + 255) / 256), 256, 0, stream>>>(csr_src, csr_dst, xl, xr,
                                                                   att + (size_t)L * HEADS * CPH, score);
        k_node_agg<<<N_NODES, 128, 0, stream>>>(rowst, csr_src, score, xl,
                                                gs + (size_t)L * HID, bs + (size_t)L * HID,
                                                h, out, (L == 1) ? 1 : 0);
    }
}

// Round 4
// 398.656 us; speedup vs baseline: 1.4495x; 1.0580x over previous
//
#include <hip/hip_runtime.h>
#include <hip/hip_bf16.h>

#define N_NODES 50000
#define E_EDGES 800000
#define ET (E_EDGES + N_NODES)   /* 850000 edges incl self loops */
#define IN_DIM 128
#define HID 96
#define HEADS 2
#define CPH 48
#define NEG_SLOPE 0.2f
#define LN_EPS 1e-5f

typedef __hip_bfloat16 bf16;
typedef short short8 __attribute__((ext_vector_type(8)));
typedef short bf16x8 __attribute__((ext_vector_type(8)));
typedef float f32x4 __attribute__((ext_vector_type(4)));
typedef unsigned short ushort_t;

__device__ __forceinline__ float us2f(unsigned short u) {
    union { unsigned int i; float f; } v; v.i = ((unsigned int)u) << 16; return v.f;
}
__device__ __forceinline__ unsigned short f2bf(float f) {
    union { float f; unsigned int i; } u; u.f = f;
    unsigned int r = u.i + 0x7FFFu + ((u.i >> 16) & 1u);
    return (unsigned short)(r >> 16);
}

// ---------------- CSR build ----------------
__global__ void k_hist(const int* __restrict__ ei, int* __restrict__ deg) {
    int e = blockIdx.x * blockDim.x + threadIdx.x;
    if (e >= ET) return;
    int dst = (e < E_EDGES) ? ei[E_EDGES + e] : (e - E_EDGES);
    atomicAdd(&deg[dst], 1);
}

__global__ __launch_bounds__(1024) void k_scan(const int* __restrict__ deg,
                                               int* __restrict__ rowstart,
                                               int* __restrict__ cursor) {
    __shared__ int wsum[16];
    __shared__ int s_carry;
    int t = threadIdx.x, lane = t & 63, w = t >> 6;
    if (t == 0) s_carry = 0;
    __syncthreads();
    for (int base = 0; base < N_NODES; base += 1024) {
        int i = base + t;
        int v = (i < N_NODES) ? deg[i] : 0;
        int sv = v;
        for (int o = 1; o < 64; o <<= 1) { int u = __shfl_up(sv, o, 64); if (lane >= o) sv += u; }
        if (lane == 63) wsum[w] = sv;
        __syncthreads();
        if (w == 0) {
            int val = (lane < 16) ? wsum[lane] : 0;
            int s2 = val;
            for (int o = 1; o < 64; o <<= 1) { int u = __shfl_up(s2, o, 64); if (lane >= o) s2 += u; }
            if (lane < 16) wsum[lane] = s2 - val;            // exclusive wave prefix
        }
        __syncthreads();
        int excl = s_carry + wsum[w] + (sv - v);
        if (i < N_NODES) { rowstart[i] = excl; cursor[i] = excl; }
        __syncthreads();
        if (t == 1023) s_carry += wsum[15] + sv;
        __syncthreads();
    }
    if (t == 0) rowstart[N_NODES] = ET;
}

__global__ void k_scatter(const int* __restrict__ ei, int* __restrict__ cursor,
                          int* __restrict__ csr_src) {
    int e = blockIdx.x * blockDim.x + threadIdx.x;
    if (e >= ET) return;
    int src, dst;
    if (e < E_EDGES) { src = ei[e]; dst = ei[E_EDGES + e]; }
    else             { src = dst = e - E_EDGES; }
    int pos = atomicAdd(&cursor[dst], 1);
    csr_src[pos] = src;
}

// ---------------- weight prep: pack into 16x16x32 B-fragment order, bf16 ----------------
__global__ void k_wprep(const float* __restrict__ W0, const float* __restrict__ W1,
                        unsigned short* __restrict__ out, int NT, int total) {
    int idx = blockIdx.x * blockDim.x + threadIdx.x;
    if (idx >= total) return;
    int j = idx & 7, lane = (idx >> 3) & 63;
    int nt = (idx >> 9) % NT, ks = (idx >> 9) / NT;
    int k = ks * 32 + ((lane >> 4) << 3) + j;
    int col = nt * 16 + (lane & 15);
    float v = (col < HID) ? W0[k * HID + col] : W1[k * HID + col - HID];
    out[idx] = f2bf(v);
}

// ---------------- MFMA GEMM: A[f32, MxK] @ Bfrag -> proj(LN+ReLU->h) or xfm(->xl,xr bf16) ----------------
template<int K, int NT, bool PROJ>
__global__ __launch_bounds__(256) void k_gemm(const float* __restrict__ A,
                                              const unsigned short* __restrict__ Bfrag,
                                              const float* __restrict__ bp,
                                              const float* __restrict__ g0,
                                              const float* __restrict__ b0,
                                              float* __restrict__ hout,
                                              bf16* __restrict__ xl,
                                              bf16* __restrict__ xr) {
    constexpr int KS = K / 32;
    int t = threadIdx.x, l = t & 63, w = t >> 6;
    int row0 = blockIdx.x * 64 + w * 16;
    int arow = row0 + (l & 15);
    if (arow > N_NODES - 1) arow = N_NODES - 1;
    int kb = (l >> 4) * 8;
    const float* ap = A + (long)arow * K + kb;
    bf16x8 a[KS];
    #pragma unroll
    for (int ks = 0; ks < KS; ks++) {
        float4 f0 = *(const float4*)(ap + ks * 32);
        float4 f1 = *(const float4*)(ap + ks * 32 + 4);
        bf16x8 av;
        av[0] = (short)f2bf(f0.x); av[1] = (short)f2bf(f0.y);
        av[2] = (short)f2bf(f0.z); av[3] = (short)f2bf(f0.w);
        av[4] = (short)f2bf(f1.x); av[5] = (short)f2bf(f1.y);
        av[6] = (short)f2bf(f1.z); av[7] = (short)f2bf(f1.w);
        a[ks] = av;
    }
    f32x4 acc[NT];
    #pragma unroll
    for (int nt = 0; nt < NT; nt++) acc[nt] = (f32x4){0.f, 0.f, 0.f, 0.f};
    #pragma unroll
    for (int nt = 0; nt < NT; nt++) {
        #pragma unroll
        for (int ks = 0; ks < KS; ks++) {
            bf16x8 b = *(const bf16x8*)(Bfrag + (((long)(ks * NT + nt) * 64 + l) << 3));
            acc[nt] = __builtin_amdgcn_mfma_f32_16x16x32_bf16(a[ks], b, acc[nt], 0, 0, 0);
        }
    }
    int rg = l >> 4, cl = l & 15;
    if constexpr (PROJ) {
        float bpv[NT], g0v[NT], b0v[NT];
        #pragma unroll
        for (int nt = 0; nt < NT; nt++) {
            int col = nt * 16 + cl;
            bpv[nt] = bp[col]; g0v[nt] = g0[col]; b0v[nt] = b0[col];
        }
        #pragma unroll
        for (int r = 0; r < 4; r++) {
            float s = 0.f, sq = 0.f;
            #pragma unroll
            for (int nt = 0; nt < NT; nt++) {
                float v = acc[nt][r] + bpv[nt];
                acc[nt][r] = v; s += v; sq += v * v;
            }
            #pragma unroll
            for (int o = 1; o <= 8; o <<= 1) { s += __shfl_xor(s, o, 64); sq += __shfl_xor(sq, o, 64); }
            float mu = s / (float)HID;
            float var = sq / (float)HID - mu * mu;
            float rstd = rsqrtf(var + LN_EPS);
            int row = row0 + rg * 4 + r;
            if (row < N_NODES) {
                #pragma unroll
                for (int nt = 0; nt < NT; nt++) {
                    float y = (acc[nt][r] - mu) * rstd * g0v[nt] + b0v[nt];
                    hout[(long)row * HID + nt * 16 + cl] = fmaxf(y, 0.f);
                }
            }
        }
    } else {
        #pragma unroll
        for (int r = 0; r < 4; r++) {
            int row = row0 + rg * 4 + r;
            if (row < N_NODES) {
                #pragma unroll
                for (int nt = 0; nt < NT; nt++) {
                    int col = nt * 16 + cl;
                    unsigned short v = f2bf(acc[nt][r]);
                    if (col < HID) ((unsigned short*)xl)[(long)row * HID + col] = v;
                    else           ((unsigned short*)xr)[(long)row * HID + col - HID] = v;
                }
            }
        }
    }
}

// ---------------- fused: edge scores + online softmax + aggregate + LN + ELU + residual ----------------
// One wave per node; 4 independent waves per block; no LDS, no __syncthreads.
// Lane layout: halves = heads. lane = hh*32 + j; lane j of each half scores edge (base+j).
__global__ __launch_bounds__(256) void k_node_fused(const int* __restrict__ rowstart,
                                                    const int* __restrict__ csr_src,
                                                    const bf16* __restrict__ xl,
                                                    const bf16* __restrict__ xr,
                                                    const float* __restrict__ att,
                                                    const float* __restrict__ gs,
                                                    const float* __restrict__ bs,
                                                    float* __restrict__ h,
                                                    float* __restrict__ out,
                                                    int write_out) {
    int t = threadIdx.x, lane = t & 63, w = t >> 6;
    int n = blockIdx.x * 4 + w;                    // grid = N/4 exact
    int j = lane & 31, hh = lane >> 5;
    int rs = rowstart[n], re = rowstart[n + 1];
    const ushort_t* xrr = (const ushort_t*)xr + (long)n * HID + hh * CPH;
    const float* ar = att + hh * CPH;
    float M = -INFINITY, D = 0.f;
    float acc_a = 0.f, acc_b = 0.f;
    int c_a = lane;                                 // 0..63
    int c_b = 64 + lane;                            // valid lane<32

    for (int base = rs; base < re; base += 32) {
        int L = min(32, re - base);
        int srcj = (j < L) ? csr_src[base + j] : 0;
        float s = -INFINITY;
        if (j < L) {
            const ushort_t* xlr = (const ushort_t*)xl + (long)srcj * HID + hh * CPH;
            s = 0.f;
            #pragma unroll
            for (int v = 0; v < 6; v++) {
                short8 a = *(const short8*)(xlr + v * 8);
                short8 b = *(const short8*)(xrr + v * 8);
                float4 t0 = *(const float4*)(ar + v * 8);
                float4 t1 = *(const float4*)(ar + v * 8 + 4);
                float av[8] = {t0.x, t0.y, t0.z, t0.w, t1.x, t1.y, t1.z, t1.w};
                #pragma unroll
                for (int q = 0; q < 8; q++) {
                    float xv = us2f((unsigned short)a[q]) + us2f((unsigned short)b[q]);
                    xv = (xv > 0.f) ? xv : NEG_SLOPE * xv;
                    s += av[q] * xv;
                }
            }
        }
        // online softmax update, per 32-lane half (= per head)
        float m = s;
        #pragma unroll
        for (int o = 1; o <= 16; o <<= 1) m = fmaxf(m, __shfl_xor(m, o, 64));
        float newM = fmaxf(M, m);
        float scale = expf(M - newM);               // exp(-inf)=0 on first chunk
        float p = (j < L) ? expf(s - newM) : 0.f;
        float sum = p;
        #pragma unroll
        for (int o = 1; o <= 16; o <<= 1) sum += __shfl_xor(sum, o, 64);
        D = D * scale + sum;
        M = newM;
        float sc0 = __shfl(scale, 0, 64), sc1 = __shfl(scale, 32, 64);
        acc_a *= (c_a < CPH) ? sc0 : sc1;
        acc_b *= sc1;
        // aggregate: lane owns channels c_a (and c_b for lane<32)
        for (int i = 0; i < L; i++) {
            int si = __shfl(srcj, i, 64);
            float p0 = __shfl(p, i, 64);
            float p1 = __shfl(p, i + 32, 64);
            const ushort_t* row = (const ushort_t*)xl + (long)si * HID;
            acc_a += ((c_a < CPH) ? p0 : p1) * us2f(row[c_a]);
            if (lane < 32) acc_b += p1 * us2f(row[c_b]);
        }
    }
    float D0 = __shfl(D, 0, 64), D1 = __shfl(D, 32, 64);
    float oa = acc_a / ((c_a < CPH) ? D0 : D1);
    float ob = (lane < 32) ? acc_b / D1 : 0.f;
    // LayerNorm over 96 channels via full-wave reduce
    float s1 = oa + ob, s2 = oa * oa + ob * ob;
    #pragma unroll
    for (int o = 1; o <= 32; o <<= 1) { s1 += __shfl_xor(s1, o, 64); s2 += __shfl_xor(s2, o, 64); }
    float mu = s1 / (float)HID;
    float var = s2 / (float)HID - mu * mu;
    float rstd = rsqrtf(var + LN_EPS);
    long baseo = (long)n * HID;
    {
        float y = (oa - mu) * rstd * gs[c_a] + bs[c_a];
        float hn = (y > 0.f) ? y : expm1f(y);
        float hv = h[baseo + c_a] + hn;
        h[baseo + c_a] = hv;
        if (write_out) out[baseo + c_a] = hv;
    }
    if (lane < 32) {
        float y = (ob - mu) * rstd * gs[c_b] + bs[c_b];
        float hn = (y > 0.f) ? y : expm1f(y);
        float hv = h[baseo + c_b] + hn;
        h[baseo + c_b] = hv;
        if (write_out) out[baseo + c_b] = hv;
    }
}

extern "C" void kernel_launch(void* const* d_in, const int* in_sizes, int n_in,
                              void* d_out, int out_size, void* d_ws, size_t ws_size,
                              hipStream_t stream) {
    const float* x   = (const float*)d_in[0];
    const int*   ei  = (const int*)d_in[1];
    const float* Wp  = (const float*)d_in[2];
    const float* bp  = (const float*)d_in[3];
    const float* g0  = (const float*)d_in[4];
    const float* b0  = (const float*)d_in[5];
    const float* Wl  = (const float*)d_in[6];
    const float* Wr  = (const float*)d_in[7];
    const float* att = (const float*)d_in[8];
    const float* gs  = (const float*)d_in[9];
    const float* bs  = (const float*)d_in[10];
    float* out = (float*)d_out;

    char* wsp = (char*)d_ws;
    size_t off = 0;
    auto alloc = [&](size_t bytes) { void* p = wsp + off; off += (bytes + 255) / 256 * 256; return p; };
    float* h        = (float*)alloc((size_t)N_NODES * HID * 4);
    bf16*  xl       = (bf16*) alloc((size_t)N_NODES * HID * 2);
    bf16*  xr       = (bf16*) alloc((size_t)N_NODES * HID * 2);
    int*   deg      = (int*)  alloc((size_t)N_NODES * 4);
    int*   rowst    = (int*)  alloc((size_t)(N_NODES + 1) * 4);
    int*   cursor   = (int*)  alloc((size_t)N_NODES * 4);
    int*   csr_src  = (int*)  alloc((size_t)ET * 4);
    unsigned short* wp_frag = (unsigned short*)alloc((size_t)IN_DIM * HID * 2);
    unsigned short* wc_frag = (unsigned short*)alloc((size_t)2 * HID * 2 * HID * 2);

    hipMemsetAsync(deg, 0, (size_t)N_NODES * 4, stream);
    k_hist<<<(ET + 255) / 256, 256, 0, stream>>>(ei, deg);
    k_scan<<<1, 1024, 0, stream>>>(deg, rowst, cursor);
    k_scatter<<<(ET + 255) / 256, 256, 0, stream>>>(ei, cursor, csr_src);

    const int WPTOT = IN_DIM * HID;            // KS=4, NT=6
    const int WCTOT = HID * 2 * HID;           // per layer: KS=3, NT=12
    k_wprep<<<(WPTOT + 255) / 256, 256, 0, stream>>>(Wp, Wp, wp_frag, 6, WPTOT);
    for (int L = 0; L < 2; L++)
        k_wprep<<<(WCTOT + 255) / 256, 256, 0, stream>>>(Wl + (size_t)L * HID * HID,
                                                         Wr + (size_t)L * HID * HID,
                                                         wc_frag + (size_t)L * WCTOT, 12, WCTOT);

    const int GBLK = (N_NODES + 63) / 64;
    k_gemm<IN_DIM, 6, true><<<GBLK, 256, 0, stream>>>(x, wp_frag, bp, g0, b0, h, nullptr, nullptr);
    for (int L = 0; L < 2; L++) {
        k_gemm<HID, 12, false><<<GBLK, 256, 0, stream>>>(h, wc_frag + (size_t)L * WCTOT,
                                                         nullptr, nullptr, nullptr, nullptr, xl, xr);
        k_node_fused<<<N_NODES / 4, 256, 0, stream>>>(rowst, csr_src, xl, xr,
                                                      att + (size_t)L * HEADS * CPH,
                                                      gs + (size_t)L * HID, bs + (size_t)L * HID,
                                                      h, out, (L == 1) ? 1 : 0);
    }
}

// Round 5
// 343.994 us; speedup vs baseline: 1.6798x; 1.1589x over previous
//
#include <hip/hip_runtime.h>
#include <hip/hip_bf16.h>

#define N_NODES 50000
#define E_EDGES 800000
#define ET (E_EDGES + N_NODES)   /* 850000 edges incl self loops */
#define IN_DIM 128
#define HID 96
#define HEADS 2
#define CPH 48
#define NEG_SLOPE 0.2f
#define LN_EPS 1e-5f
#define LROW 52                  /* LDS row stride in dwords: 16B-aligned, bank-spread */

typedef __hip_bfloat16 bf16;
typedef short bf16x8 __attribute__((ext_vector_type(8)));
typedef float f32x4 __attribute__((ext_vector_type(4)));
typedef _Float16 h16;
typedef h16 h16x2 __attribute__((ext_vector_type(2)));
typedef h16 h16x8 __attribute__((ext_vector_type(8)));

#if __has_builtin(__builtin_amdgcn_fdot2)
#define HAS_FDOT2 1
#else
#define HAS_FDOT2 0
#endif

__device__ __forceinline__ unsigned short f2bf(float f) {
    union { float f; unsigned int i; } u; u.f = f;
    unsigned int r = u.i + 0x7FFFu + ((u.i >> 16) & 1u);
    return (unsigned short)(r >> 16);
}

// ---------------- CSR build ----------------
__global__ void k_hist(const int* __restrict__ ei, int* __restrict__ deg) {
    int e = blockIdx.x * blockDim.x + threadIdx.x;
    if (e >= ET) return;
    int dst = (e < E_EDGES) ? ei[E_EDGES + e] : (e - E_EDGES);
    atomicAdd(&deg[dst], 1);
}

__global__ __launch_bounds__(1024) void k_scan(const int* __restrict__ deg,
                                               int* __restrict__ rowstart,
                                               int* __restrict__ cursor) {
    __shared__ int wsum[16];
    __shared__ int s_carry;
    int t = threadIdx.x, lane = t & 63, w = t >> 6;
    if (t == 0) s_carry = 0;
    __syncthreads();
    for (int base = 0; base < N_NODES; base += 1024) {
        int i = base + t;
        int v = (i < N_NODES) ? deg[i] : 0;
        int sv = v;
        for (int o = 1; o < 64; o <<= 1) { int u = __shfl_up(sv, o, 64); if (lane >= o) sv += u; }
        if (lane == 63) wsum[w] = sv;
        __syncthreads();
        if (w == 0) {
            int val = (lane < 16) ? wsum[lane] : 0;
            int s2 = val;
            for (int o = 1; o < 64; o <<= 1) { int u = __shfl_up(s2, o, 64); if (lane >= o) s2 += u; }
            if (lane < 16) wsum[lane] = s2 - val;            // exclusive wave prefix
        }
        __syncthreads();
        int excl = s_carry + wsum[w] + (sv - v);
        if (i < N_NODES) { rowstart[i] = excl; cursor[i] = excl; }
        __syncthreads();
        if (t == 1023) s_carry += wsum[15] + sv;
        __syncthreads();
    }
    if (t == 0) rowstart[N_NODES] = ET;
}

__global__ void k_scatter(const int* __restrict__ ei, int* __restrict__ cursor,
                          int* __restrict__ csr_src) {
    int e = blockIdx.x * blockDim.x + threadIdx.x;
    if (e >= ET) return;
    int src, dst;
    if (e < E_EDGES) { src = ei[e]; dst = ei[E_EDGES + e]; }
    else             { src = dst = e - E_EDGES; }
    int pos = atomicAdd(&cursor[dst], 1);
    csr_src[pos] = src;
}

// ---------------- weight prep: pack into 16x16x32 B-fragment order, bf16 ----------------
__global__ void k_wprep(const float* __restrict__ W0, const float* __restrict__ W1,
                        unsigned short* __restrict__ out, int NT, int total) {
    int idx = blockIdx.x * blockDim.x + threadIdx.x;
    if (idx >= total) return;
    int j = idx & 7, lane = (idx >> 3) & 63;
    int nt = (idx >> 9) % NT, ks = (idx >> 9) / NT;
    int k = ks * 32 + ((lane >> 4) << 3) + j;
    int col = nt * 16 + (lane & 15);
    float v = (col < HID) ? W0[k * HID + col] : W1[k * HID + col - HID];
    out[idx] = f2bf(v);
}

// ---------------- MFMA GEMM: A[f32, MxK] @ Bfrag -> proj(LN+ReLU->h) or xfm(->xl,xr fp16) ----------------
template<int K, int NT, bool PROJ>
__global__ __launch_bounds__(256) void k_gemm(const float* __restrict__ A,
                                              const unsigned short* __restrict__ Bfrag,
                                              const float* __restrict__ bp,
                                              const float* __restrict__ g0,
                                              const float* __restrict__ b0,
                                              float* __restrict__ hout,
                                              h16* __restrict__ xl,
                                              h16* __restrict__ xr) {
    constexpr int KS = K / 32;
    int t = threadIdx.x, l = t & 63, w = t >> 6;
    int row0 = blockIdx.x * 64 + w * 16;
    int arow = row0 + (l & 15);
    if (arow > N_NODES - 1) arow = N_NODES - 1;
    int kb = (l >> 4) * 8;
    const float* ap = A + (long)arow * K + kb;
    bf16x8 a[KS];
    #pragma unroll
    for (int ks = 0; ks < KS; ks++) {
        float4 f0 = *(const float4*)(ap + ks * 32);
        float4 f1 = *(const float4*)(ap + ks * 32 + 4);
        bf16x8 av;
        av[0] = (short)f2bf(f0.x); av[1] = (short)f2bf(f0.y);
        av[2] = (short)f2bf(f0.z); av[3] = (short)f2bf(f0.w);
        av[4] = (short)f2bf(f1.x); av[5] = (short)f2bf(f1.y);
        av[6] = (short)f2bf(f1.z); av[7] = (short)f2bf(f1.w);
        a[ks] = av;
    }
    f32x4 acc[NT];
    #pragma unroll
    for (int nt = 0; nt < NT; nt++) acc[nt] = (f32x4){0.f, 0.f, 0.f, 0.f};
    #pragma unroll
    for (int nt = 0; nt < NT; nt++) {
        #pragma unroll
        for (int ks = 0; ks < KS; ks++) {
            bf16x8 b = *(const bf16x8*)(Bfrag + (((long)(ks * NT + nt) * 64 + l) << 3));
            acc[nt] = __builtin_amdgcn_mfma_f32_16x16x32_bf16(a[ks], b, acc[nt], 0, 0, 0);
        }
    }
    int rg = l >> 4, cl = l & 15;
    if constexpr (PROJ) {
        float bpv[NT], g0v[NT], b0v[NT];
        #pragma unroll
        for (int nt = 0; nt < NT; nt++) {
            int col = nt * 16 + cl;
            bpv[nt] = bp[col]; g0v[nt] = g0[col]; b0v[nt] = b0[col];
        }
        #pragma unroll
        for (int r = 0; r < 4; r++) {
            float s = 0.f, sq = 0.f;
            #pragma unroll
            for (int nt = 0; nt < NT; nt++) {
                float v = acc[nt][r] + bpv[nt];
                acc[nt][r] = v; s += v; sq += v * v;
            }
            #pragma unroll
            for (int o = 1; o <= 8; o <<= 1) { s += __shfl_xor(s, o, 64); sq += __shfl_xor(sq, o, 64); }
            float mu = s / (float)HID;
            float var = sq / (float)HID - mu * mu;
            float rstd = rsqrtf(var + LN_EPS);
            int row = row0 + rg * 4 + r;
            if (row < N_NODES) {
                #pragma unroll
                for (int nt = 0; nt < NT; nt++) {
                    float y = (acc[nt][r] - mu) * rstd * g0v[nt] + b0v[nt];
                    hout[(long)row * HID + nt * 16 + cl] = fmaxf(y, 0.f);
                }
            }
        }
    } else {
        #pragma unroll
        for (int r = 0; r < 4; r++) {
            int row = row0 + rg * 4 + r;
            if (row < N_NODES) {
                #pragma unroll
                for (int nt = 0; nt < NT; nt++) {
                    int col = nt * 16 + cl;
                    h16 v = (h16)acc[nt][r];
                    if (col < HID) xl[(long)row * HID + col] = v;
                    else           xr[(long)row * HID + col - HID] = v;
                }
            }
        }
    }
}

// ---------------- fused: edge scores + online softmax + aggregate + LN + ELU + residual ----------------
// One wave per node; 4 waves/block, each with a private LDS tile; no __syncthreads.
// Score: lane = hh*32+j scores edge (base+j) for head hh, staging the xl row slice to LDS.
// Agg:   lane l<48 owns channel pair {2l,2l+1}, reads staged rows from LDS.
__global__ __launch_bounds__(256) void k_node_fused(const int* __restrict__ rowstart,
                                                    const int* __restrict__ csr_src,
                                                    const h16* __restrict__ xl,
                                                    const h16* __restrict__ xr,
                                                    const float* __restrict__ att,
                                                    const float* __restrict__ gs,
                                                    const float* __restrict__ bs,
                                                    float* __restrict__ h,
                                                    float* __restrict__ out,
                                                    int write_out) {
    __shared__ h16x2 lds[4 * 32 * LROW];
    int t = threadIdx.x, lane = t & 63, w = t >> 6;
    h16x2* slds = lds + w * 32 * LROW;
    int n = blockIdx.x * 4 + w;                    // grid = N/4 exact
    int j = lane & 31, hh = lane >> 5;
    int rs = rowstart[n], re = rowstart[n + 1];

    // target row (this node) and attention vector for this lane's head, held in regs
    const h16x8* xrr = (const h16x8*)(xr + (long)n * HID + hh * CPH);
    h16x8 xrv[6];
    #pragma unroll
    for (int v = 0; v < 6; v++) xrv[v] = xrr[v];
    const float* ar = att + hh * CPH;
    h16x8 attv[6];
    #pragma unroll
    for (int v = 0; v < 6; v++) {
        float4 t0 = *(const float4*)(ar + v * 8);
        float4 t1 = *(const float4*)(ar + v * 8 + 4);
        attv[v] = (h16x8){(h16)t0.x, (h16)t0.y, (h16)t0.z, (h16)t0.w,
                          (h16)t1.x, (h16)t1.y, (h16)t1.z, (h16)t1.w};
    }

    float M = -INFINITY, D = 0.f;                  // per 32-lane half = per head
    int l = lane;
    int lc = (l < 48) ? l : 47;                    // pair index owned (lanes>=48 shadow lane 47)
    float2 acc = {0.f, 0.f};

    for (int base = rs; base < re; base += 32) {
        int L = min(32, re - base);
        int srcj = csr_src[base + min(j, L - 1)];
        const h16x8* xlr = (const h16x8*)(xl + (long)srcj * HID + hh * CPH);
        float s0 = 0.f, s1 = 0.f;
#if !HAS_FDOT2
        h16x8 sacc = (h16x8)(h16)0.f;
#endif
        #pragma unroll
        for (int v = 0; v < 6; v++) {
            h16x8 xa = xlr[v];
            // stage to LDS: dword offset j*LROW + hh*24 + v*4 (16B aligned)
            *(h16x8*)(slds + j * LROW + hh * 24 + v * 4) = xa;
            h16x8 sum = xa + xrv[v];
            h16x8 lk = __builtin_elementwise_max(sum, sum * (h16)NEG_SLOPE);
#if HAS_FDOT2
            s0 = __builtin_amdgcn_fdot2(__builtin_shufflevector(lk, lk, 0, 1),
                                        __builtin_shufflevector(attv[v], attv[v], 0, 1), s0, false);
            s1 = __builtin_amdgcn_fdot2(__builtin_shufflevector(lk, lk, 2, 3),
                                        __builtin_shufflevector(attv[v], attv[v], 2, 3), s1, false);
            s0 = __builtin_amdgcn_fdot2(__builtin_shufflevector(lk, lk, 4, 5),
                                        __builtin_shufflevector(attv[v], attv[v], 4, 5), s0, false);
            s1 = __builtin_amdgcn_fdot2(__builtin_shufflevector(lk, lk, 6, 7),
                                        __builtin_shufflevector(attv[v], attv[v], 6, 7), s1, false);
#else
            sacc += lk * attv[v];
#endif
        }
#if !HAS_FDOT2
        {
            h16x2 p0 = __builtin_shufflevector(sacc, sacc, 0, 1);
            h16x2 p1 = __builtin_shufflevector(sacc, sacc, 2, 3);
            h16x2 p2 = __builtin_shufflevector(sacc, sacc, 4, 5);
            h16x2 p3 = __builtin_shufflevector(sacc, sacc, 6, 7);
            h16x2 q = (p0 + p1) + (p2 + p3);
            s0 = (float)q.x + (float)q.y; s1 = 0.f;
        }
#endif
        float s = (j < L) ? (s0 + s1) : -INFINITY;

        // online softmax update within each 32-lane half
        float m = s;
        #pragma unroll
        for (int o = 1; o <= 16; o <<= 1) m = fmaxf(m, __shfl_xor(m, o, 64));
        float newM = fmaxf(M, m);
        float scale = expf(M - newM);               // exp(-inf)=0 on first chunk
        float p = (j < L) ? expf(s - newM) : 0.f;
        float sum = p;
        #pragma unroll
        for (int o = 1; o <= 16; o <<= 1) sum += __shfl_xor(sum, o, 64);
        D = D * scale + sum;
        M = newM;

        float sc0 = __shfl(scale, 0, 64), sc1 = __shfl(scale, 32, 64);
        float myscale = (lc < 24) ? sc0 : sc1;
        acc.x *= myscale; acc.y *= myscale;
        int psrc = (lc < 24) ? 0 : 32;
        // aggregate from LDS-staged rows
        #pragma unroll 4
        for (int i = 0; i < L; i++) {
            float pi = __shfl(p, psrc + i, 64);
            h16x2 hv = slds[i * LROW + lc];
            acc.x += pi * (float)hv.x;
            acc.y += pi * (float)hv.y;
        }
    }
    float D0 = __shfl(D, 0, 64), D1 = __shfl(D, 32, 64);
    float myD = (lc < 24) ? D0 : D1;
    float oa = acc.x / myD, ob = acc.y / myD;
    bool act = (l < 48);
    if (!act) { oa = 0.f; ob = 0.f; }
    // LayerNorm over 96 channels via full-wave reduce
    float s1r = oa + ob, s2r = oa * oa + ob * ob;
    #pragma unroll
    for (int o = 1; o <= 32; o <<= 1) { s1r += __shfl_xor(s1r, o, 64); s2r += __shfl_xor(s2r, o, 64); }
    float mu = s1r / (float)HID;
    float var = s2r / (float)HID - mu * mu;
    float rstd = rsqrtf(var + LN_EPS);
    if (act) {
        long baseo = (long)n * HID + 2 * l;
        float2 g = *(const float2*)(gs + 2 * l);
        float2 b = *(const float2*)(bs + 2 * l);
        float y0 = (oa - mu) * rstd * g.x + b.x;
        float y1 = (ob - mu) * rstd * g.y + b.y;
        float hn0 = (y0 > 0.f) ? y0 : expm1f(y0);
        float hn1 = (y1 > 0.f) ? y1 : expm1f(y1);
        float2 hold = *(float2*)(h + baseo);
        float2 hv = {hold.x + hn0, hold.y + hn1};
        *(float2*)(h + baseo) = hv;
        if (write_out) *(float2*)(out + baseo) = hv;
    }
}

extern "C" void kernel_launch(void* const* d_in, const int* in_sizes, int n_in,
                              void* d_out, int out_size, void* d_ws, size_t ws_size,
                              hipStream_t stream) {
    const float* x   = (const float*)d_in[0];
    const int*   ei  = (const int*)d_in[1];
    const float* Wp  = (const float*)d_in[2];
    const float* bp  = (const float*)d_in[3];
    const float* g0  = (const float*)d_in[4];
    const float* b0  = (const float*)d_in[5];
    const float* Wl  = (const float*)d_in[6];
    const float* Wr  = (const float*)d_in[7];
    const float* att = (const float*)d_in[8];
    const float* gs  = (const float*)d_in[9];
    const float* bs  = (const float*)d_in[10];
    float* out = (float*)d_out;

    char* wsp = (char*)d_ws;
    size_t off = 0;
    auto alloc = [&](size_t bytes) { void* p = wsp + off; off += (bytes + 255) / 256 * 256; return p; };
    float* h        = (float*)alloc((size_t)N_NODES * HID * 4);
    h16*   xl       = (h16*)  alloc((size_t)N_NODES * HID * 2);
    h16*   xr       = (h16*)  alloc((size_t)N_NODES * HID * 2);
    int*   deg      = (int*)  alloc((size_t)N_NODES * 4);
    int*   rowst    = (int*)  alloc((size_t)(N_NODES + 1) * 4);
    int*   cursor   = (int*)  alloc((size_t)N_NODES * 4);
    int*   csr_src  = (int*)  alloc((size_t)ET * 4);
    unsigned short* wp_frag = (unsigned short*)alloc((size_t)IN_DIM * HID * 2);
    unsigned short* wc_frag = (unsigned short*)alloc((size_t)2 * HID * 2 * HID * 2);

    hipMemsetAsync(deg, 0, (size_t)N_NODES * 4, stream);
    k_hist<<<(ET + 255) / 256, 256, 0, stream>>>(ei, deg);
    k_scan<<<1, 1024, 0, stream>>>(deg, rowst, cursor);
    k_scatter<<<(ET + 255) / 256, 256, 0, stream>>>(ei, cursor, csr_src);

    const int WPTOT = IN_DIM * HID;            // KS=4, NT=6
    const int WCTOT = HID * 2 * HID;           // per layer: KS=3, NT=12
    k_wprep<<<(WPTOT + 255) / 256, 256, 0, stream>>>(Wp, Wp, wp_frag, 6, WPTOT);
    for (int L = 0; L < 2; L++)
        k_wprep<<<(WCTOT + 255) / 256, 256, 0, stream>>>(Wl + (size_t)L * HID * HID,
                                                         Wr + (size_t)L * HID * HID,
                                                         wc_frag + (size_t)L * WCTOT, 12, WCTOT);

    const int GBLK = (N_NODES + 63) / 64;
    k_gemm<IN_DIM, 6, true><<<GBLK, 256, 0, stream>>>(x, wp_frag, bp, g0, b0, h, nullptr, nullptr);
    for (int L = 0; L < 2; L++) {
        k_gemm<HID, 12, false><<<GBLK, 256, 0, stream>>>(h, wc_frag + (size_t)L * WCTOT,
                                                         nullptr, nullptr, nullptr, nullptr, xl, xr);
        k_node_fused<<<N_NODES / 4, 256, 0, stream>>>(rowst, csr_src, xl, xr,
                                                      att + (size_t)L * HEADS * CPH,
                                                      gs + (size_t)L * HID, bs + (size_t)L * HID,
                                                      h, out, (L == 1) ? 1 : 0);
    }
}